// Round 1
// baseline (367.294 us; speedup 1.0000x reference)
//
#include <hip/hip_runtime.h>
#include <stdint.h>

#define IN_F   11008
#define OUT_F  4096
#define TOPK_K 5504
#define NCACHE 64
#define MASK_WORDS 344   // 11008 / 32

// ws layout (bytes):
//   [0    , 1376) : topk mask bits (344 u32)
//   [1408 , 1412) : packed score u32, atomicMax of (inter<<6)|(63-row)
//   [1536 , 1536+44032) : counts (int per feature, multiplicity of best cached row)

__device__ __forceinline__ unsigned absbits(float v) {
    return __float_as_uint(v) & 0x7fffffffu;
}

// ---------------------------------------------------------------------------
// K0: exact radix-select of the 5504-th largest |x| (uint-encoded), build the
// top-k mask with index-ordered tie-breaking (matches jax.lax.top_k), zero the
// counts array and the score slot. Single block, 1024 threads.
// ---------------------------------------------------------------------------
__global__ __launch_bounds__(1024) void k_select(const float* __restrict__ x,
                                                 unsigned* __restrict__ maskbits_g,
                                                 unsigned* __restrict__ score_g,
                                                 int* __restrict__ counts_g) {
    __shared__ unsigned hist[16][256];   // per-wave private hists (exponent byte is hot)
    __shared__ unsigned sh_T;
    __shared__ unsigned sh_rem;
    __shared__ unsigned maskb[MASK_WORDS];
    __shared__ unsigned waveCnt[16];
    __shared__ unsigned runEq;

    const int tid  = threadIdx.x;
    const int wv   = tid >> 6;
    const int lane = tid & 63;

    unsigned prefix = 0, maskHi = 0, remaining = TOPK_K;

    for (int pass = 3; pass >= 0; --pass) {
        for (int b = tid; b < 16 * 256; b += 1024) ((unsigned*)hist)[b] = 0;
        __syncthreads();
        for (int i = tid; i < IN_F; i += 1024) {
            unsigned key = absbits(x[i]);
            if ((key & maskHi) == prefix)
                atomicAdd(&hist[wv][(key >> (pass * 8)) & 255], 1u);
        }
        __syncthreads();
        for (int b = tid; b < 256; b += 1024) {
            unsigned s = 0;
            for (int w = 0; w < 16; ++w) s += hist[w][b];
            hist[0][b] = s;
        }
        __syncthreads();
        if (tid == 0) {
            unsigned acc = 0;
            int sel = 0;
            for (int b = 255; b >= 0; --b) {
                unsigned c = hist[0][b];
                if (acc + c >= remaining) { sel = b; sh_rem = remaining - acc; break; }
                acc += c;
            }
            sh_T = prefix | ((unsigned)sel << (pass * 8));
        }
        __syncthreads();
        prefix = sh_T;
        maskHi |= 0xffu << (pass * 8);
        remaining = sh_rem;
        __syncthreads();
    }

    const unsigned T = prefix;        // exact key of the k-th largest
    const unsigned eqTake = remaining; // #(key==T) elements to take, ascending index

    for (int w = tid; w < MASK_WORDS; w += 1024) maskb[w] = 0;
    if (tid == 0) runEq = 0;
    __syncthreads();

    for (int base = 0; base < IN_F; base += 1024) {
        int i = base + tid;
        bool valid = i < IN_F;
        unsigned key = valid ? absbits(x[i]) : 0u;
        bool gt = valid && (key > T);
        bool eq = valid && (key == T);
        unsigned long long bal = __ballot(eq);
        if (lane == 0) waveCnt[wv] = (unsigned)__popcll(bal);
        __syncthreads();
        unsigned pre = runEq;
        for (int w = 0; w < wv; ++w) pre += waveCnt[w];
        unsigned rank = pre + (unsigned)__popcll(bal & ((1ull << lane) - 1ull));
        if (gt || (eq && rank < eqTake))
            atomicOr(&maskb[i >> 5], 1u << (i & 31));
        __syncthreads();
        if (tid == 0) {
            unsigned tot = 0;
            for (int w = 0; w < 16; ++w) tot += waveCnt[w];
            runEq += tot;
        }
        __syncthreads();
    }

    for (int w = tid; w < MASK_WORDS; w += 1024) maskbits_g[w] = maskb[w];
    for (int i = tid; i < IN_F; i += 1024) counts_g[i] = 0;
    if (tid == 0) *score_g = 0;
}

// ---------------------------------------------------------------------------
// K1: recall per cached row via bitmask intersection (dedupes duplicates),
// argmax with lowest-row tie-break via packed atomicMax. 64 blocks x 256.
// ---------------------------------------------------------------------------
__global__ __launch_bounds__(256) void k_recall(const int* __restrict__ cached,
                                                const unsigned* __restrict__ maskbits_g,
                                                unsigned* __restrict__ score_g) {
    __shared__ unsigned rowbits[MASK_WORDS];
    __shared__ unsigned wsum[4];
    const int r = blockIdx.x;
    const int tid = threadIdx.x;
    for (int w = tid; w < MASK_WORDS; w += 256) rowbits[w] = 0;
    __syncthreads();
    const int* ci = cached + r * TOPK_K;
    for (int t = tid; t < TOPK_K; t += 256) {
        int idx = ci[t];
        atomicOr(&rowbits[idx >> 5], 1u << (idx & 31));
    }
    __syncthreads();
    unsigned cnt = 0;
    for (int w = tid; w < MASK_WORDS; w += 256) cnt += __popc(rowbits[w] & maskbits_g[w]);
    for (int off = 32; off > 0; off >>= 1) cnt += __shfl_down(cnt, off, 64);
    if ((tid & 63) == 0) wsum[tid >> 6] = cnt;
    __syncthreads();
    if (tid == 0) {
        unsigned tot = wsum[0] + wsum[1] + wsum[2] + wsum[3];
        atomicMax(score_g, (tot << 6) | (unsigned)(63 - r));
    }
}

// ---------------------------------------------------------------------------
// K2: multiplicity histogram of the best cached row (used only if recall>=0.9,
// computed unconditionally). 22 blocks x 256.
// ---------------------------------------------------------------------------
__global__ __launch_bounds__(256) void k_counts(const int* __restrict__ cached,
                                                const unsigned* __restrict__ score_g,
                                                int* __restrict__ counts_g) {
    unsigned score = *score_g;
    int best = 63 - (int)(score & 63u);
    int t = blockIdx.x * 256 + threadIdx.x;
    if (t < TOPK_K) atomicAdd(&counts_g[cached[best * TOPK_K + t]], 1);
}

// ---------------------------------------------------------------------------
// K3: dense GEMV out = W * (coef .* x) + bias. coef = mask (topk path) or
// multiplicity counts (cached path) — exactly reproduces duplicate columns.
// 512 blocks x 256 threads; xc staged in 44KB LDS; 1 wave per 2 output rows.
// ---------------------------------------------------------------------------
#define ROWS_PER_BLOCK 8
__global__ __launch_bounds__(256) void k_gemv(const float* __restrict__ x,
                                              const float* __restrict__ W,
                                              const float* __restrict__ bias,
                                              const unsigned* __restrict__ maskbits_g,
                                              const unsigned* __restrict__ score_g,
                                              const int* __restrict__ counts_g,
                                              float* __restrict__ out) {
    __shared__ __align__(16) float xs[IN_F];
    const int tid = threadIdx.x;

    unsigned score = *score_g;
    unsigned inter = score >> 6;
    bool useCache = ((float)inter / (float)TOPK_K) >= 0.9f;

    const float4* x4 = (const float4*)x;
    for (int j = tid; j < IN_F / 4; j += 256) {
        float4 xv = x4[j];
        int base = j * 4;
        float c0, c1, c2, c3;
        if (useCache) {
            c0 = (float)counts_g[base + 0];
            c1 = (float)counts_g[base + 1];
            c2 = (float)counts_g[base + 2];
            c3 = (float)counts_g[base + 3];
        } else {
            unsigned wbits = maskbits_g[base >> 5];  // 4 consecutive bits share a word
            int sh = base & 31;
            c0 = (float)((wbits >> (sh + 0)) & 1u);
            c1 = (float)((wbits >> (sh + 1)) & 1u);
            c2 = (float)((wbits >> (sh + 2)) & 1u);
            c3 = (float)((wbits >> (sh + 3)) & 1u);
        }
        xs[base + 0] = xv.x * c0;
        xs[base + 1] = xv.y * c1;
        xs[base + 2] = xv.z * c2;
        xs[base + 3] = xv.w * c3;
    }
    __syncthreads();

    const int wv   = tid >> 6;
    const int lane = tid & 63;
    const int row0 = blockIdx.x * ROWS_PER_BLOCK + wv * 2;
    const int row1 = row0 + 1;
    const float4* w0p = (const float4*)(W + (size_t)row0 * IN_F);
    const float4* w1p = (const float4*)(W + (size_t)row1 * IN_F);
    const float4* xs4 = (const float4*)xs;

    float acc0 = 0.f, acc1 = 0.f;
#pragma unroll 4
    for (int j = lane; j < IN_F / 4; j += 64) {   // exactly 43 iters/lane
        float4 xv = xs4[j];
        float4 a  = w0p[j];
        float4 b  = w1p[j];
        acc0 += xv.x * a.x + xv.y * a.y + xv.z * a.z + xv.w * a.w;
        acc1 += xv.x * b.x + xv.y * b.y + xv.z * b.z + xv.w * b.w;
    }
    for (int off = 32; off > 0; off >>= 1) {
        acc0 += __shfl_down(acc0, off, 64);
        acc1 += __shfl_down(acc1, off, 64);
    }
    if (lane == 0) {
        out[row0] = acc0 + bias[row0];
        out[row1] = acc1 + bias[row1];
    }
}

extern "C" void kernel_launch(void* const* d_in, const int* in_sizes, int n_in,
                              void* d_out, int out_size, void* d_ws, size_t ws_size,
                              hipStream_t stream) {
    const float* x      = (const float*)d_in[0];
    const float* W      = (const float*)d_in[1];
    const float* bias   = (const float*)d_in[2];
    const int*   cached = (const int*)d_in[3];
    float* out = (float*)d_out;

    char* ws = (char*)d_ws;
    unsigned* maskbits = (unsigned*)(ws + 0);
    unsigned* score    = (unsigned*)(ws + 1408);
    int*      counts   = (int*)(ws + 1536);

    k_select<<<1, 1024, 0, stream>>>(x, maskbits, score, counts);
    k_recall<<<NCACHE, 256, 0, stream>>>(cached, maskbits, score);
    k_counts<<<(TOPK_K + 255) / 256, 256, 0, stream>>>(cached, score, counts);
    k_gemv<<<OUT_F / ROWS_PER_BLOCK, 256, 0, stream>>>(x, W, bias, maskbits, score, counts, out);
}